// Round 2
// baseline (191.038 us; speedup 1.0000x reference)
//
#include <hip/hip_runtime.h>
#include <hip/hip_bf16.h>

// Head: out[b,t,h] = softmax_causal( (x@Wq)(x@Wk)^T * 6^-0.5 ) @ (x@Wv)
// B=512 T=128 C=384 H=64. One block per b, bf16 MFMA 16x16x32.
//
// V3: occupancy + per-wave load-chain fix.
//  - 512 threads (8 waves) per block -> 16 waves/CU (grid fixed at 512 = 2 blocks/CU,
//    so bigger blocks are the only occupancy lever). __launch_bounds__(512,4) keeps
//    VGPR <= 128 so both blocks stay resident.
//  - Phase 1 split 2(m)x4(n): each wave 64 rows x 48 cols -> only 3 Wt-fragment
//    loads per chunk (V2 had 12 dependent global B-loads/chunk/wave = the stall).
//  - Wt stays pre-built bf16 in exact MFMA B-fragment order (build_wt pre-kernel).
//  - Phase 2: one 16-row tile per wave (was 2), halving serial softmax chain.

#define B_ 512
#define T_ 128
#define C_ 384
#define H_ 64

typedef __bf16 bf16;
typedef __attribute__((ext_vector_type(8))) __bf16 bf16x8;
typedef __attribute__((ext_vector_type(4))) __bf16 bf16x4;
typedef __attribute__((ext_vector_type(4))) float f32x4;

// ---------------- pre-kernel: W -> bf16 W^T in MFMA B-fragment order --------
// Wt[((kc*12 + tn)*64 + lane)*8 + e] = Wsel[(kc*32 + quad*8 + e)*64 + h]
//   lane = quad*16+lm, n = tn*16+lm, j = n>>6 selects Wq/Wk/Wv, h = n&63.
__global__ void build_wt(const float* __restrict__ Wq, const float* __restrict__ Wk,
                         const float* __restrict__ Wv, bf16* __restrict__ Wt)
{
    int t = blockIdx.x * 256 + threadIdx.x;   // 9216 threads total
    if (t >= 12 * 12 * 64) return;
    int lane = t & 63;
    int tn   = (t >> 6) % 12;
    int kc   = t / (12 * 64);
    int lm = lane & 15, quad = lane >> 4;
    int n = tn * 16 + lm;
    int j = n >> 6, h = n & 63;
    const float* Wp = (j == 0) ? Wq : (j == 1) ? Wk : Wv;
    int k0 = kc * 32 + quad * 8;
    bf16x8 v;
#pragma unroll
    for (int e = 0; e < 8; ++e) v[e] = (bf16)Wp[(k0 + e) * H_ + h];
    *(bf16x8*)&Wt[t * 8] = v;
}

// LDS element offsets (bf16):
//  Qs  [0,8192)      : 128 x 64, XOR-swizzled units of 8
//  Ks  [8192,16384)  : 128 x 64, swizzled
//  Vts [16384,24576) : 64 x 128 (V^T), swizzled
//  Ps  aliases [0,16384) : 128 x 128, swizzled  (after barrier)
// total 49152 bytes -> 2 blocks/CU (96KB of 160KB)

__launch_bounds__(512, 4)
__global__ void head_fused(const float* __restrict__ x,
                           const bf16* __restrict__ Wt,
                           float* __restrict__ out)
{
    __shared__ bf16 lds[24576];
    bf16* Qs  = lds;
    bf16* Ks  = lds + 8192;
    bf16* Vts = lds + 16384;
    bf16* Ps  = lds;            // aliases Qs+Ks after barrier

    const int tid  = threadIdx.x;
    const int w    = tid >> 6;     // wave 0..7
    const int lane = tid & 63;
    const int lm   = lane & 15;    // fragment row/col index
    const int quad = lane >> 4;    // fragment k-group / row-group
    const int mg   = w >> 2;       // m-group 0..1 (64 rows each)
    const int ng   = w & 3;        // n-group 0..3 (3 tiles each)
    const int b    = blockIdx.x;

    const float* xb = x + (size_t)b * (T_ * C_);

    // ================= Phase 1: QKV = x[b] @ [Wq|Wk|Wv] =================
    // wave (mg,ng): m rows [64mg, 64mg+64), n tiles {3ng, 3ng+1, 3ng+2}.
    // No LDS, no barriers.
    f32x4 acc[4][3];
#pragma unroll
    for (int mf = 0; mf < 4; ++mf)
#pragma unroll
        for (int nf = 0; nf < 3; ++nf) acc[mf][nf] = (f32x4){0.f, 0.f, 0.f, 0.f};

    const float* xr   = xb + (size_t)(64 * mg + lm) * C_ + quad * 8;
    const bf16*  wbase = Wt + (size_t)(3 * ng) * 512 + lane * 8;  // tile stride 512 elem

    float4 buf[8];   // constant-indexed only -> registers
    auto LD = [&](int kc) {
#pragma unroll
        for (int mf = 0; mf < 4; ++mf) {
            const float4* p = (const float4*)(xr + mf * 16 * C_ + kc * 32);
            buf[2 * mf]     = p[0];
            buf[2 * mf + 1] = p[1];
        }
    };

    LD(0);
#pragma unroll
    for (int kc = 0; kc < 12; ++kc) {
        bf16x8 afr[4];
#pragma unroll
        for (int mf = 0; mf < 4; ++mf) {
            float4 p0 = buf[2 * mf], p1 = buf[2 * mf + 1];
            afr[mf] = (bf16x8){(bf16)p0.x, (bf16)p0.y, (bf16)p0.z, (bf16)p0.w,
                               (bf16)p1.x, (bf16)p1.y, (bf16)p1.z, (bf16)p1.w};
        }
        if (kc < 11) LD(kc + 1);   // prefetch next chunk while MFMAs run
#pragma unroll
        for (int nf = 0; nf < 3; ++nf) {
            bf16x8 bfr = *(const bf16x8*)(wbase + (size_t)kc * 6144 + nf * 512);
#pragma unroll
            for (int mf = 0; mf < 4; ++mf)
                acc[mf][nf] =
                    __builtin_amdgcn_mfma_f32_16x16x32_bf16(afr[mf], bfr, acc[mf][nf], 0, 0, 0);
        }
    }

    // epilogue: Q,K row-major [t][h]; V transposed [h][t]; all swizzled bf16
#pragma unroll
    for (int mf = 0; mf < 4; ++mf) {
#pragma unroll
        for (int nf = 0; nf < 3; ++nf) {
            int tn = 3 * ng + nf;
            int gn = 16 * tn + lm;
            int j = gn >> 6, h = gn & 63;   // j wave-uniform per nf
            int m0 = 64 * mg + 16 * mf + quad * 4;
            if (j == 2) {
                bf16x4 v4 = {(bf16)acc[mf][nf][0], (bf16)acc[mf][nf][1],
                             (bf16)acc[mf][nf][2], (bf16)acc[mf][nf][3]};
                int pc = (m0 & 7) | ((((m0 >> 3) ^ (h & 15)) & 15) << 3);
                *(bf16x4*)&Vts[h * 128 + pc] = v4;
            } else {
                bf16* dst = (j == 0) ? Qs : Ks;
#pragma unroll
                for (int r = 0; r < 4; ++r) {
                    int m = m0 + r;
                    int pc = (h & 7) | ((((h >> 3) ^ (m & 7)) & 7) << 3);
                    dst[m * 64 + pc] = (bf16)acc[mf][nf][r];
                }
            }
        }
    }
    __syncthreads();

    // ================= Phase 2: attention =================
    // wave w owns q-tile tm = w (16 rows).
    const float SCALE = 0.40824829046386307f;  // 6^-0.5
    const int tm = w;
    const int mrow = 16 * tm + lm;

    f32x4 sacc[8];
#pragma unroll
    for (int t = 0; t < 8; ++t) sacc[t] = (f32x4){0.f, 0.f, 0.f, 0.f};

    // S = Q K^T  (skip fully-masked tiles; tn<=tm is wave-uniform)
    bf16x8 qa[2];
#pragma unroll
    for (int ks = 0; ks < 2; ++ks) {
        int phys = ((ks * 4 + quad) ^ (mrow & 7)) & 7;
        qa[ks] = *(const bf16x8*)&Qs[mrow * 64 + phys * 8];
    }
#pragma unroll
    for (int tn = 0; tn < 8; ++tn) {
        if (tn <= tm) {
            int nrow = 16 * tn + lm;
#pragma unroll
            for (int ks = 0; ks < 2; ++ks) {
                int phys = ((ks * 4 + quad) ^ (nrow & 7)) & 7;
                bf16x8 kb = *(const bf16x8*)&Ks[nrow * 64 + phys * 8];
                sacc[tn] =
                    __builtin_amdgcn_mfma_f32_16x16x32_bf16(qa[ks], kb, sacc[tn], 0, 0, 0);
            }
        }
    }

    // softmax, fully in registers; rows live in contiguous 16-lane groups
#pragma unroll
    for (int r = 0; r < 4; ++r) {
        int m = 16 * tm + quad * 4 + r;
        float mx = -1e30f;
#pragma unroll
        for (int tn = 0; tn < 8; ++tn) {
            if (tn <= tm) {
                int n = 16 * tn + lm;
                float v = (n <= m) ? sacc[tn][r] * SCALE : -1e30f;
                sacc[tn][r] = v;
                mx = fmaxf(mx, v);
            }
        }
#pragma unroll
        for (int off = 1; off < 16; off <<= 1) mx = fmaxf(mx, __shfl_xor(mx, off, 16));
        float sum = 0.f;
#pragma unroll
        for (int tn = 0; tn < 8; ++tn) {
            if (tn <= tm) {
                float e = __expf(sacc[tn][r] - mx);
                sacc[tn][r] = e;
                sum += e;
            }
        }
#pragma unroll
        for (int off = 1; off < 16; off <<= 1) sum += __shfl_xor(sum, off, 16);
        float inv = 1.f / sum;
#pragma unroll
        for (int tn = 0; tn < 8; ++tn) {
            if (tn <= tm) sacc[tn][r] *= inv;
        }
    }

    __syncthreads();  // everyone done reading Qs/Ks; Ps aliases them

    // write P (bf16, swizzled). Each wave writes only its own rows.
#pragma unroll
    for (int tn = 0; tn < 8; ++tn) {
        if (tn <= tm) {
            int n = 16 * tn + lm;
#pragma unroll
            for (int r = 0; r < 4; ++r) {
                int m = 16 * tm + quad * 4 + r;
                int pc = (n & 7) | ((((n >> 3) ^ (m & 15)) & 15) << 3);
                Ps[m * 128 + pc] = (bf16)sacc[tn][r];
            }
        }
    }
    if ((tm & 1) == 0) {  // zero the half-covered k-tile (tm even)
        int m = 16 * tm + lm;
        int c0 = 16 * (tm + 1) + quad * 4;
        int pc = (c0 & 7) | ((((c0 >> 3) ^ (m & 15)) & 15) << 3);
        *(bf16x4*)&Ps[m * 128 + pc] =
            (bf16x4){(bf16)0.f, (bf16)0.f, (bf16)0.f, (bf16)0.f};
    }

    // O = P @ V  (k-tiles limited by causal extent; reads only own P rows,
    // which this wave itself wrote -> no barrier needed before PV)
    f32x4 oacc[4];
#pragma unroll
    for (int t = 0; t < 4; ++t) oacc[t] = (f32x4){0.f, 0.f, 0.f, 0.f};

    const int nks = (tm + 2) >> 1;
    for (int ks = 0; ks < nks; ++ks) {  // wave-uniform bound
        int unit = ks * 4 + quad;
        int phys = (unit ^ (mrow & 15)) & 15;
        bf16x8 pa = *(const bf16x8*)&Ps[mrow * 128 + phys * 8];
#pragma unroll
        for (int th = 0; th < 4; ++th) {
            int hrow = 16 * th + lm;
            int ph2 = (unit ^ (hrow & 15)) & 15;
            bf16x8 vb = *(const bf16x8*)&Vts[hrow * 128 + ph2 * 8];
            oacc[th] =
                __builtin_amdgcn_mfma_f32_16x16x32_bf16(pa, vb, oacc[th], 0, 0, 0);
        }
    }

    // store O fp32 [b][t][h]
    float* ob = out + (size_t)b * (T_ * H_);
#pragma unroll
    for (int th = 0; th < 4; ++th) {
        int h = 16 * th + lm;
#pragma unroll
        for (int r = 0; r < 4; ++r) {
            int m = 16 * tm + quad * 4 + r;
            ob[m * 64 + h] = oacc[th][r];
        }
    }
}

extern "C" void kernel_launch(void* const* d_in, const int* in_sizes, int n_in,
                              void* d_out, int out_size, void* d_ws, size_t ws_size,
                              hipStream_t stream) {
    const float* x  = (const float*)d_in[0];
    const float* Wq = (const float*)d_in[1];
    const float* Wk = (const float*)d_in[2];
    const float* Wv = (const float*)d_in[3];
    float* o = (float*)d_out;
    bf16* Wt = (bf16*)d_ws;   // needs 147456 bytes
    build_wt<<<dim3(36), dim3(256), 0, stream>>>(Wq, Wk, Wv, Wt);
    head_fused<<<dim3(B_), dim3(512), 0, stream>>>(x, Wt, o);
}

// Round 3
// 171.118 us; speedup vs baseline: 1.1164x; 1.1164x over previous
//
#include <hip/hip_runtime.h>
#include <hip/hip_bf16.h>

// Head: out[b,t,h] = softmax_causal( (x@Wq)(x@Wk)^T * 6^-0.5 ) @ (x@Wv)
// B=512 T=128 C=384 H=64. One block per b, bf16 MFMA 16x16x32.
//
// V4: fix memory-level parallelism on the x stream (the real bottleneck).
//  - x staged into LDS via __builtin_amdgcn_global_load_lds (fire-and-forget,
//    no VGPR cost), 3-buffer pipeline, 2 chunks in flight, counted
//    s_waitcnt vmcnt(2) + RAW s_barrier in the k-loop (__syncthreads would
//    drain vmcnt(0) and kill the pipeline).
//  - x read ONCE per block (was 4x redundant across n-group waves).
//  - XOR-swizzled 16B units: swizzle applied on the GLOBAL source address
//    (global_load_lds dest must be linear), same XOR on the LDS read.
//  - staging buffers (3x16KB) alias the Q/K/Vt/P region (used only after the
//    k-loop) -> LDS stays 48KB, 2 blocks/CU, 16 waves/CU.
//  - Wt stays pre-built bf16 in exact MFMA B-fragment order (build_wt).

#define B_ 512
#define T_ 128
#define C_ 384
#define H_ 64

typedef __bf16 bf16;
typedef __attribute__((ext_vector_type(8))) __bf16 bf16x8;
typedef __attribute__((ext_vector_type(4))) __bf16 bf16x4;
typedef __attribute__((ext_vector_type(4))) float f32x4;

#define GLOAD_LDS16(g, l)                                                     \
    __builtin_amdgcn_global_load_lds(                                         \
        (const __attribute__((address_space(1))) void*)(g),                   \
        (__attribute__((address_space(3))) void*)(l), 16, 0, 0)

// ---------------- pre-kernel: W -> bf16 W^T in MFMA B-fragment order --------
// Wt[((kc*12 + tn)*64 + lane)*8 + e] = Wsel[(kc*32 + quad*8 + e)*64 + h]
__global__ void build_wt(const float* __restrict__ Wq, const float* __restrict__ Wk,
                         const float* __restrict__ Wv, bf16* __restrict__ Wt)
{
    int t = blockIdx.x * 256 + threadIdx.x;
    if (t >= 12 * 12 * 64) return;
    int lane = t & 63;
    int tn   = (t >> 6) % 12;
    int kc   = t / (12 * 64);
    int lm = lane & 15, quad = lane >> 4;
    int n = tn * 16 + lm;
    int j = n >> 6, h = n & 63;
    const float* Wp = (j == 0) ? Wq : (j == 1) ? Wk : Wv;
    int k0 = kc * 32 + quad * 8;
    bf16x8 v;
#pragma unroll
    for (int e = 0; e < 8; ++e) v[e] = (bf16)Wp[(k0 + e) * H_ + h];
    *(bf16x8*)&Wt[t * 8] = v;
}

// LDS element offsets (bf16), 49152 bytes total -> 2 blocks/CU:
//  during k-loop : 3 x 16KB fp32 x-staging buffers  (bytes [0,49152))
//  after k-loop  : Qs [0,8192) elems, Ks [8192,16384), Vts [16384,24576)
//                  Ps aliases [0,16384) after softmax barrier

__launch_bounds__(512, 4)
__global__ void head_fused(const float* __restrict__ x,
                           const bf16* __restrict__ Wt,
                           float* __restrict__ out)
{
    __shared__ __align__(16) bf16 lds[24576];
    bf16* Qs  = lds;
    bf16* Ks  = lds + 8192;
    bf16* Vts = lds + 16384;
    bf16* Ps  = lds;
    float* xstage = (float*)lds;   // 3 x 4096 floats (16KB each)

    const int tid  = threadIdx.x;
    const int w    = tid >> 6;     // wave 0..7
    const int lane = tid & 63;
    const int lm   = lane & 15;
    const int quad = lane >> 4;
    const int mg   = w >> 2;       // m-group 0..1 (64 rows each)
    const int ng   = w & 3;        // n-group 0..3 (3 tiles each)
    const int b    = blockIdx.x;

    const float* xb = x + (size_t)b * (T_ * C_);

    // ================= Phase 1: QKV = x[b] @ [Wq|Wk|Wv] =================
    f32x4 acc[4][3];
#pragma unroll
    for (int mf = 0; mf < 4; ++mf)
#pragma unroll
        for (int nf = 0; nf < 3; ++nf) acc[mf][nf] = (f32x4){0.f, 0.f, 0.f, 0.f};

    const bf16* wbase = Wt + (size_t)(3 * ng) * 512 + lane * 8;

    // stage chunk kc (128 rows x 32 cols fp32, 16KB) into buffer kc%3.
    // thread does 2x 16B loads; LDS dest linear (wave-uniform base + lane*16),
    // source column-unit pre-swizzled: srcunit = unit ^ (row & 7).
    const int u0row = tid >> 3, u0unit = tid & 7;             // i=0: u=tid
    const int u1row = (tid + 512) >> 3, u1unit = tid & 7;     // i=1: u=tid+512
    const float* g0 = xb + (size_t)u0row * C_ + (u0unit ^ (u0row & 7)) * 4;
    const float* g1 = xb + (size_t)u1row * C_ + (u1unit ^ (u1row & 7)) * 4;
    char* l0 = (char*)lds + (size_t)(w * 64) * 16;            // + buf*16384
    char* l1 = (char*)lds + (size_t)(512 + w * 64) * 16;

    auto STAGE = [&](int kc) {
        int bo = (kc % 3) * 16384;
        GLOAD_LDS16(g0 + kc * 32, l0 + bo);
        GLOAD_LDS16(g1 + kc * 32, l1 + bo);
    };

    STAGE(0);
    STAGE(1);
    asm volatile("s_waitcnt vmcnt(2)" ::: "memory");   // chunk 0 complete
    __builtin_amdgcn_s_barrier();

#pragma unroll
    for (int kc = 0; kc < 12; ++kc) {
        if (kc + 2 < 12) STAGE(kc + 2);

        const float* xc = xstage + (kc % 3) * 4096;
        bf16x8 afr[4];
#pragma unroll
        for (int mf = 0; mf < 4; ++mf) {
            int row = 64 * mg + 16 * mf + lm;
            int p0 = (2 * quad) ^ (row & 7);
            int p1 = (2 * quad + 1) ^ (row & 7);
            f32x4 va = *(const f32x4*)(xc + row * 32 + p0 * 4);
            f32x4 vb = *(const f32x4*)(xc + row * 32 + p1 * 4);
            afr[mf] = (bf16x8){(bf16)va[0], (bf16)va[1], (bf16)va[2], (bf16)va[3],
                               (bf16)vb[0], (bf16)vb[1], (bf16)vb[2], (bf16)vb[3]};
        }
#pragma unroll
        for (int nf = 0; nf < 3; ++nf) {
            bf16x8 bfr = *(const bf16x8*)(wbase + (size_t)kc * 6144 + nf * 512);
#pragma unroll
            for (int mf = 0; mf < 4; ++mf)
                acc[mf][nf] =
                    __builtin_amdgcn_mfma_f32_16x16x32_bf16(afr[mf], bfr, acc[mf][nf], 0, 0, 0);
        }

        if (kc < 11) {
            if (kc < 10) asm volatile("s_waitcnt vmcnt(2)" ::: "memory");
            else         asm volatile("s_waitcnt vmcnt(0)" ::: "memory");
            __builtin_amdgcn_s_barrier();
        }
    }
    __syncthreads();   // full drain; staging buffers die, Q/K/Vt region live

    // epilogue: Q,K row-major [t][h]; V transposed [h][t]; all swizzled bf16
#pragma unroll
    for (int mf = 0; mf < 4; ++mf) {
#pragma unroll
        for (int nf = 0; nf < 3; ++nf) {
            int tn = 3 * ng + nf;
            int gn = 16 * tn + lm;
            int j = gn >> 6, h = gn & 63;
            int m0 = 64 * mg + 16 * mf + quad * 4;
            if (j == 2) {
                bf16x4 v4 = {(bf16)acc[mf][nf][0], (bf16)acc[mf][nf][1],
                             (bf16)acc[mf][nf][2], (bf16)acc[mf][nf][3]};
                int pc = (m0 & 7) | ((((m0 >> 3) ^ (h & 15)) & 15) << 3);
                *(bf16x4*)&Vts[h * 128 + pc] = v4;
            } else {
                bf16* dst = (j == 0) ? Qs : Ks;
#pragma unroll
                for (int r = 0; r < 4; ++r) {
                    int m = m0 + r;
                    int pc = (h & 7) | ((((h >> 3) ^ (m & 7)) & 7) << 3);
                    dst[m * 64 + pc] = (bf16)acc[mf][nf][r];
                }
            }
        }
    }
    __syncthreads();

    // ================= Phase 2: attention =================
    const float SCALE = 0.40824829046386307f;  // 6^-0.5
    const int tm = w;
    const int mrow = 16 * tm + lm;

    f32x4 sacc[8];
#pragma unroll
    for (int t = 0; t < 8; ++t) sacc[t] = (f32x4){0.f, 0.f, 0.f, 0.f};

    bf16x8 qa[2];
#pragma unroll
    for (int ks = 0; ks < 2; ++ks) {
        int phys = ((ks * 4 + quad) ^ (mrow & 7)) & 7;
        qa[ks] = *(const bf16x8*)&Qs[mrow * 64 + phys * 8];
    }
#pragma unroll
    for (int tn = 0; tn < 8; ++tn) {
        if (tn <= tm) {
            int nrow = 16 * tn + lm;
#pragma unroll
            for (int ks = 0; ks < 2; ++ks) {
                int phys = ((ks * 4 + quad) ^ (nrow & 7)) & 7;
                bf16x8 kb = *(const bf16x8*)&Ks[nrow * 64 + phys * 8];
                sacc[tn] =
                    __builtin_amdgcn_mfma_f32_16x16x32_bf16(qa[ks], kb, sacc[tn], 0, 0, 0);
            }
        }
    }

    // softmax, fully in registers
#pragma unroll
    for (int r = 0; r < 4; ++r) {
        int m = 16 * tm + quad * 4 + r;
        float mx = -1e30f;
#pragma unroll
        for (int tn = 0; tn < 8; ++tn) {
            if (tn <= tm) {
                int n = 16 * tn + lm;
                float v = (n <= m) ? sacc[tn][r] * SCALE : -1e30f;
                sacc[tn][r] = v;
                mx = fmaxf(mx, v);
            }
        }
#pragma unroll
        for (int off = 1; off < 16; off <<= 1) mx = fmaxf(mx, __shfl_xor(mx, off, 16));
        float sum = 0.f;
#pragma unroll
        for (int tn = 0; tn < 8; ++tn) {
            if (tn <= tm) {
                float e = __expf(sacc[tn][r] - mx);
                sacc[tn][r] = e;
                sum += e;
            }
        }
#pragma unroll
        for (int off = 1; off < 16; off <<= 1) sum += __shfl_xor(sum, off, 16);
        float inv = 1.f / sum;
#pragma unroll
        for (int tn = 0; tn < 8; ++tn) {
            if (tn <= tm) sacc[tn][r] *= inv;
        }
    }

    __syncthreads();  // everyone done reading Qs/Ks; Ps aliases them

    // write P (bf16, swizzled); each wave writes only its own rows
#pragma unroll
    for (int tn = 0; tn < 8; ++tn) {
        if (tn <= tm) {
            int n = 16 * tn + lm;
#pragma unroll
            for (int r = 0; r < 4; ++r) {
                int m = 16 * tm + quad * 4 + r;
                int pc = (n & 7) | ((((n >> 3) ^ (m & 15)) & 15) << 3);
                Ps[m * 128 + pc] = (bf16)sacc[tn][r];
            }
        }
    }
    if ((tm & 1) == 0) {  // zero the half-covered k-tile (tm even)
        int m = 16 * tm + lm;
        int c0 = 16 * (tm + 1) + quad * 4;
        int pc = (c0 & 7) | ((((c0 >> 3) ^ (m & 15)) & 15) << 3);
        *(bf16x4*)&Ps[m * 128 + pc] =
            (bf16x4){(bf16)0.f, (bf16)0.f, (bf16)0.f, (bf16)0.f};
    }

    // O = P @ V  (reads only own P rows -> no barrier needed before PV)
    f32x4 oacc[4];
#pragma unroll
    for (int t = 0; t < 4; ++t) oacc[t] = (f32x4){0.f, 0.f, 0.f, 0.f};

    const int nks = (tm + 2) >> 1;
    for (int ks = 0; ks < nks; ++ks) {  // wave-uniform bound
        int unit = ks * 4 + quad;
        int phys = (unit ^ (mrow & 15)) & 15;
        bf16x8 pa = *(const bf16x8*)&Ps[mrow * 128 + phys * 8];
#pragma unroll
        for (int th = 0; th < 4; ++th) {
            int hrow = 16 * th + lm;
            int ph2 = (unit ^ (hrow & 15)) & 15;
            bf16x8 vb = *(const bf16x8*)&Vts[hrow * 128 + ph2 * 8];
            oacc[th] =
                __builtin_amdgcn_mfma_f32_16x16x32_bf16(pa, vb, oacc[th], 0, 0, 0);
        }
    }

    // store O fp32 [b][t][h]
    float* ob = out + (size_t)b * (T_ * H_);
#pragma unroll
    for (int th = 0; th < 4; ++th) {
        int h = 16 * th + lm;
#pragma unroll
        for (int r = 0; r < 4; ++r) {
            int m = 16 * tm + quad * 4 + r;
            ob[m * 64 + h] = oacc[th][r];
        }
    }
}

extern "C" void kernel_launch(void* const* d_in, const int* in_sizes, int n_in,
                              void* d_out, int out_size, void* d_ws, size_t ws_size,
                              hipStream_t stream) {
    const float* x  = (const float*)d_in[0];
    const float* Wq = (const float*)d_in[1];
    const float* Wk = (const float*)d_in[2];
    const float* Wv = (const float*)d_in[3];
    float* o = (float*)d_out;
    bf16* Wt = (bf16*)d_ws;   // needs 147456 bytes
    build_wt<<<dim3(36), dim3(256), 0, stream>>>(Wq, Wk, Wv, Wt);
    head_fused<<<dim3(B_), dim3(512), 0, stream>>>(x, Wt, o);
}

// Round 4
// 168.160 us; speedup vs baseline: 1.1360x; 1.0176x over previous
//
#include <hip/hip_runtime.h>
#include <hip/hip_bf16.h>

// Head: out[b,t,h] = softmax_causal( (x@Wq)(x@Wk)^T * 6^-0.5 ) @ (x@Wv)
// B=512 T=128 C=384 H=64. One block per b, bf16 MFMA 16x16x32.
//
// V5: pure-LDS k-loop (fix V4's vmcnt poisoning).
//  - V4 bug: in-loop Wt VGPR global loads sat BEHIND the stage loads in the
//    vmcnt FIFO; compiler waits for Wt forced a full drain every iteration ->
//    pipeline depth 0. V5 stages Wt chunks via global_load_lds as well, so the
//    loop's ONLY vmem ops are fire-and-forget stage loads; counted pipeline
//    works as designed.
//  - 2 buffers x 28KB (x 16KB fp32-swizzled + Wt 12KB linear), STAGE(kc+1) at
//    top of iter, s_waitcnt vmcnt(0) + RAW s_barrier at bottom (one full
//    iteration of latency slack; __syncthreads would also drain lgkm).
//  - LDS 56KB, aliased by Q/K/Vt/P region after the loop -> 2 blocks/CU.
//  - x read once per block; Wt B-fragments now contiguous ds_read_b128.

#define B_ 512
#define T_ 128
#define C_ 384
#define H_ 64

typedef __bf16 bf16;
typedef __attribute__((ext_vector_type(8))) __bf16 bf16x8;
typedef __attribute__((ext_vector_type(4))) __bf16 bf16x4;
typedef __attribute__((ext_vector_type(4))) float f32x4;

#define GLOAD_LDS16(g, l)                                                     \
    __builtin_amdgcn_global_load_lds(                                         \
        (const __attribute__((address_space(1))) void*)(g),                   \
        (__attribute__((address_space(3))) void*)(l), 16, 0, 0)

// ---------------- pre-kernel: W -> bf16 W^T in MFMA B-fragment order --------
// Wt[((kc*12 + tn)*64 + lane)*8 + e] = Wsel[(kc*32 + quad*8 + e)*64 + h]
__global__ void build_wt(const float* __restrict__ Wq, const float* __restrict__ Wk,
                         const float* __restrict__ Wv, bf16* __restrict__ Wt)
{
    int t = blockIdx.x * 256 + threadIdx.x;
    if (t >= 12 * 12 * 64) return;
    int lane = t & 63;
    int tn   = (t >> 6) % 12;
    int kc   = t / (12 * 64);
    int lm = lane & 15, quad = lane >> 4;
    int n = tn * 16 + lm;
    int j = n >> 6, h = n & 63;
    const float* Wp = (j == 0) ? Wq : (j == 1) ? Wk : Wv;
    int k0 = kc * 32 + quad * 8;
    bf16x8 v;
#pragma unroll
    for (int e = 0; e < 8; ++e) v[e] = (bf16)Wp[(k0 + e) * H_ + h];
    *(bf16x8*)&Wt[t * 8] = v;
}

// LDS (57344 bytes total -> 2 blocks/CU):
//  k-loop, buffer p in {0,1} at byte bufbase = p*28672:
//    x  [bufbase, bufbase+16384)    : 128 rows x 8 swizzled 16B units (fp32)
//    Wt [bufbase+16384, +12288)     : linear copy of 12KB Wt chunk
//  after k-loop (aliases staging):
//    Qs [0,8192) elems, Ks [8192,16384), Vts [16384,24576), Ps aliases [0,16384)

__launch_bounds__(512, 4)
__global__ void head_fused(const float* __restrict__ x,
                           const bf16* __restrict__ Wt,
                           float* __restrict__ out)
{
    __shared__ __align__(16) bf16 lds[28672];
    bf16* Qs  = lds;
    bf16* Ks  = lds + 8192;
    bf16* Vts = lds + 16384;
    bf16* Ps  = lds;

    const int tid  = threadIdx.x;
    const int w    = tid >> 6;     // wave 0..7
    const int lane = tid & 63;
    const int lm   = lane & 15;
    const int quad = lane >> 4;
    const int mg   = w >> 2;       // m-group 0..1 (64 rows each)
    const int ng   = w & 3;        // n-group 0..3 (3 tiles each)
    const int b    = blockIdx.x;

    const float* xb = x + (size_t)b * (T_ * C_);

    // ================= Phase 1: QKV = x[b] @ [Wq|Wk|Wv] =================
    f32x4 acc[4][3];
#pragma unroll
    for (int mf = 0; mf < 4; ++mf)
#pragma unroll
        for (int nf = 0; nf < 3; ++nf) acc[mf][nf] = (f32x4){0.f, 0.f, 0.f, 0.f};

    // ---- staging addresses ----
    // x: unit u in [0,1024) holds global (row=u>>3, srcunit=(u&7)^(row&7));
    //    thread t stages units t and t+512 (LDS dest linear = wave base + lane*16).
    const int r0 = tid >> 3, r1 = (tid + 512) >> 3;
    const float* gx0 = xb + (size_t)r0 * C_ + (((tid & 7) ^ (r0 & 7)) * 4);
    const float* gx1 = xb + (size_t)r1 * C_ + (((tid & 7) ^ (r1 & 7)) * 4);
    char* lx0 = (char*)lds + w * 1024;
    char* lx1 = (char*)lds + 8192 + w * 1024;
    // Wt: linear 12KB copy; thread t stages unit t; threads of waves 0..3 also
    // stage unit 512+t.
    const char* gwt = (const char*)Wt;
    char* lw0 = (char*)lds + 16384 + w * 1024;
    char* lw1 = (char*)lds + 16384 + 8192 + w * 1024;

    auto STAGE = [&](int kc) {
        int bo = (kc & 1) * 28672;
        GLOAD_LDS16(gx0 + kc * 32, lx0 + bo);
        GLOAD_LDS16(gx1 + kc * 32, lx1 + bo);
        GLOAD_LDS16(gwt + (size_t)kc * 12288 + tid * 16, lw0 + bo);
        if (w < 4)
            GLOAD_LDS16(gwt + (size_t)kc * 12288 + 8192 + tid * 16, lw1 + bo);
    };

    STAGE(0);
    asm volatile("s_waitcnt vmcnt(0)" ::: "memory");
    __builtin_amdgcn_s_barrier();

#pragma unroll
    for (int kc = 0; kc < 12; ++kc) {
        if (kc < 11) STAGE(kc + 1);   // into the other buffer, free since kc-1

        const float* xc = (const float*)((const char*)lds + (kc & 1) * 28672);
        const bf16*  wc = (const bf16*)((const char*)lds + (kc & 1) * 28672 + 16384);

        bf16x8 afr[4];
#pragma unroll
        for (int mf = 0; mf < 4; ++mf) {
            int row = 64 * mg + 16 * mf + lm;
            int p0 = (2 * quad) ^ (row & 7);
            int p1 = (2 * quad + 1) ^ (row & 7);
            f32x4 va = *(const f32x4*)(xc + row * 32 + p0 * 4);
            f32x4 vb = *(const f32x4*)(xc + row * 32 + p1 * 4);
            afr[mf] = (bf16x8){(bf16)va[0], (bf16)va[1], (bf16)va[2], (bf16)va[3],
                               (bf16)vb[0], (bf16)vb[1], (bf16)vb[2], (bf16)vb[3]};
        }
#pragma unroll
        for (int nf = 0; nf < 3; ++nf) {
            bf16x8 bfr = *(const bf16x8*)(wc + (3 * ng + nf) * 512 + lane * 8);
#pragma unroll
            for (int mf = 0; mf < 4; ++mf)
                acc[mf][nf] =
                    __builtin_amdgcn_mfma_f32_16x16x32_bf16(afr[mf], bfr, acc[mf][nf], 0, 0, 0);
        }

        if (kc < 11) {
            asm volatile("s_waitcnt vmcnt(0)" ::: "memory");  // next buffer landed
            __builtin_amdgcn_s_barrier();
        }
    }
    __syncthreads();   // staging buffers die; Q/K/Vt region becomes live

    // epilogue: Q,K row-major [t][h]; V transposed [h][t]; all swizzled bf16
#pragma unroll
    for (int mf = 0; mf < 4; ++mf) {
#pragma unroll
        for (int nf = 0; nf < 3; ++nf) {
            int tn = 3 * ng + nf;
            int gn = 16 * tn + lm;
            int j = gn >> 6, h = gn & 63;
            int m0 = 64 * mg + 16 * mf + quad * 4;
            if (j == 2) {
                bf16x4 v4 = {(bf16)acc[mf][nf][0], (bf16)acc[mf][nf][1],
                             (bf16)acc[mf][nf][2], (bf16)acc[mf][nf][3]};
                int pc = (m0 & 7) | ((((m0 >> 3) ^ (h & 15)) & 15) << 3);
                *(bf16x4*)&Vts[h * 128 + pc] = v4;
            } else {
                bf16* dst = (j == 0) ? Qs : Ks;
#pragma unroll
                for (int r = 0; r < 4; ++r) {
                    int m = m0 + r;
                    int pc = (h & 7) | ((((h >> 3) ^ (m & 7)) & 7) << 3);
                    dst[m * 64 + pc] = (bf16)acc[mf][nf][r];
                }
            }
        }
    }
    __syncthreads();

    // ================= Phase 2: attention =================
    const float SCALE = 0.40824829046386307f;  // 6^-0.5
    const int tm = w;
    const int mrow = 16 * tm + lm;

    f32x4 sacc[8];
#pragma unroll
    for (int t = 0; t < 8; ++t) sacc[t] = (f32x4){0.f, 0.f, 0.f, 0.f};

    bf16x8 qa[2];
#pragma unroll
    for (int ks = 0; ks < 2; ++ks) {
        int phys = ((ks * 4 + quad) ^ (mrow & 7)) & 7;
        qa[ks] = *(const bf16x8*)&Qs[mrow * 64 + phys * 8];
    }
#pragma unroll
    for (int tn = 0; tn < 8; ++tn) {
        if (tn <= tm) {
            int nrow = 16 * tn + lm;
#pragma unroll
            for (int ks = 0; ks < 2; ++ks) {
                int phys = ((ks * 4 + quad) ^ (nrow & 7)) & 7;
                bf16x8 kb = *(const bf16x8*)&Ks[nrow * 64 + phys * 8];
                sacc[tn] =
                    __builtin_amdgcn_mfma_f32_16x16x32_bf16(qa[ks], kb, sacc[tn], 0, 0, 0);
            }
        }
    }

    // softmax, fully in registers
#pragma unroll
    for (int r = 0; r < 4; ++r) {
        int m = 16 * tm + quad * 4 + r;
        float mx = -1e30f;
#pragma unroll
        for (int tn = 0; tn < 8; ++tn) {
            if (tn <= tm) {
                int n = 16 * tn + lm;
                float v = (n <= m) ? sacc[tn][r] * SCALE : -1e30f;
                sacc[tn][r] = v;
                mx = fmaxf(mx, v);
            }
        }
#pragma unroll
        for (int off = 1; off < 16; off <<= 1) mx = fmaxf(mx, __shfl_xor(mx, off, 16));
        float sum = 0.f;
#pragma unroll
        for (int tn = 0; tn < 8; ++tn) {
            if (tn <= tm) {
                float e = __expf(sacc[tn][r] - mx);
                sacc[tn][r] = e;
                sum += e;
            }
        }
#pragma unroll
        for (int off = 1; off < 16; off <<= 1) sum += __shfl_xor(sum, off, 16);
        float inv = 1.f / sum;
#pragma unroll
        for (int tn = 0; tn < 8; ++tn) {
            if (tn <= tm) sacc[tn][r] *= inv;
        }
    }

    __syncthreads();  // everyone done reading Qs/Ks; Ps aliases them

    // write P (bf16, swizzled); each wave writes only its own rows
#pragma unroll
    for (int tn = 0; tn < 8; ++tn) {
        if (tn <= tm) {
            int n = 16 * tn + lm;
#pragma unroll
            for (int r = 0; r < 4; ++r) {
                int m = 16 * tm + quad * 4 + r;
                int pc = (n & 7) | ((((n >> 3) ^ (m & 15)) & 15) << 3);
                Ps[m * 128 + pc] = (bf16)sacc[tn][r];
            }
        }
    }
    if ((tm & 1) == 0) {  // zero the half-covered k-tile (tm even)
        int m = 16 * tm + lm;
        int c0 = 16 * (tm + 1) + quad * 4;
        int pc = (c0 & 7) | ((((c0 >> 3) ^ (m & 15)) & 15) << 3);
        *(bf16x4*)&Ps[m * 128 + pc] =
            (bf16x4){(bf16)0.f, (bf16)0.f, (bf16)0.f, (bf16)0.f};
    }

    // O = P @ V  (reads only own P rows -> no barrier needed before PV)
    f32x4 oacc[4];
#pragma unroll
    for (int t = 0; t < 4; ++t) oacc[t] = (f32x4){0.f, 0.f, 0.f, 0.f};

    const int nks = (tm + 2) >> 1;
    for (int ks = 0; ks < nks; ++ks) {  // wave-uniform bound
        int unit = ks * 4 + quad;
        int phys = (unit ^ (mrow & 15)) & 15;
        bf16x8 pa = *(const bf16x8*)&Ps[mrow * 128 + phys * 8];
#pragma unroll
        for (int th = 0; th < 4; ++th) {
            int hrow = 16 * th + lm;
            int ph2 = (unit ^ (hrow & 15)) & 15;
            bf16x8 vb = *(const bf16x8*)&Vts[hrow * 128 + ph2 * 8];
            oacc[th] =
                __builtin_amdgcn_mfma_f32_16x16x32_bf16(pa, vb, oacc[th], 0, 0, 0);
        }
    }

    // store O fp32 [b][t][h]
    float* ob = out + (size_t)b * (T_ * H_);
#pragma unroll
    for (int th = 0; th < 4; ++th) {
        int h = 16 * th + lm;
#pragma unroll
        for (int r = 0; r < 4; ++r) {
            int m = 16 * tm + quad * 4 + r;
            ob[m * 64 + h] = oacc[th][r];
        }
    }
}

extern "C" void kernel_launch(void* const* d_in, const int* in_sizes, int n_in,
                              void* d_out, int out_size, void* d_ws, size_t ws_size,
                              hipStream_t stream) {
    const float* x  = (const float*)d_in[0];
    const float* Wq = (const float*)d_in[1];
    const float* Wk = (const float*)d_in[2];
    const float* Wv = (const float*)d_in[3];
    float* o = (float*)d_out;
    bf16* Wt = (bf16*)d_ws;   // needs 147456 bytes
    build_wt<<<dim3(36), dim3(256), 0, stream>>>(Wq, Wk, Wv, Wt);
    head_fused<<<dim3(B_), dim3(512), 0, stream>>>(x, Wt, o);
}